// Round 10
// baseline (61.272 us; speedup 1.0000x reference)
//
#include <hip/hip_runtime.h>
#include <hip/hip_bf16.h>

#define VOCAB   50257
#define NUM_DIM 1024
#define VB 64                              // vocab entries per tile
#define DB 64                              // dims per tile
#define NVCH ((VOCAB + VB - 1) / VB)       // 786 vocab chunks
#define CLCAP 96                           // list capacity per chunk (mean ~21)
#define NDCH (NUM_DIM / DB)                // 16 dim chunks

typedef float f32x4 __attribute__((ext_vector_type(4)));  // NT-store-compatible

// Swizzled tile layout (flat 16 KB): element (d,v) at elem offset
//     d*64 + (((v>>2) + (d>>2)) & 15)*4 + (v&3)
// Staging: 16x global_load_lds_dwordx4 per block, linear LDS dest
// (wave-uniform base + lane*16), per-lane PRE-ROTATED global source
// (rule 21: swizzle the source, keep LDS dest linear).
// Write phase: 4 scalar b32 reads per token-slice; per token 8 banks x2,
// ~2-4-way across the 4 parallel tokens (hidden under HBM wall).

// ---------------- scatter: bucket tokens by vocab chunk ----------------

__global__ void __launch_bounds__(256) scatter_kernel(
    const int* __restrict__ tokens, int n_tok,
    int* ccount, unsigned* clist, int* n_ov, int* ov_list)
{
    int i = blockIdx.x * 256 + threadIdx.x;
    if (i >= n_tok) return;
    int v = tokens[i];
    int ch = v >> 6;                                   // vocab chunk (VB=64)
    int slot = atomicAdd(&ccount[ch], 1);
    if (slot < CLCAP) clist[ch * CLCAP + slot] = ((unsigned)i << 6) | (unsigned)(v & 63);
    else { int p = atomicAdd(n_ov, 1); ov_list[p] = i; }
}

// ---------------- main: stream weight once, scatter to output rows ----------------

__global__ void __launch_bounds__(256, 8) embed_main(
    const float* __restrict__ weight, const float* __restrict__ bias,
    const int* __restrict__ ccount, const unsigned* __restrict__ clist,
    float* __restrict__ out,
    const int* __restrict__ tokens, const int* __restrict__ n_ov,
    const int* __restrict__ ov_list)
{
    __shared__ __align__(16) float tile[VB * DB];   // swizzled, 16 KB
    __shared__ unsigned slist[CLCAP];
    __shared__ int snn;

    int tid = threadIdx.x;
    int cv = blockIdx.y;
    int v0 = cv * VB;
    int d0 = blockIdx.x * DB;

    if (tid == 0) { int c = ccount[cv]; snn = c < CLCAP ? c : CLCAP; }
    if (tid < CLCAP) slist[tid] = clist[cv * CLCAP + tid];

    if (v0 + VB <= VOCAB) {
        // async staging: each wave issues 4x global_load_lds_dwordx4.
        // LDS chunk blk (1 KB) holds d-rows 4blk..4blk+3; lane ln writes
        // 16B at blk*1024 + ln*16 = elems (d = 4blk + (ln>>4),
        // s = ln&15, j=0..3) -> global v-group vg = ((ln&15) - blk) & 15.
        int wv = tid >> 6;                 // wave 0..3
        int ln = tid & 63;
        #pragma unroll
        for (int i = 0; i < 4; ++i) {
            int blk = (wv << 2) + i;       // 0..15, wave-uniform
            int d   = (blk << 2) + (ln >> 4);
            int vg  = ((ln & 15) - blk) & 15;
            const float* g = weight + (size_t)(d0 + d) * VOCAB + v0 + (vg << 2);
            __builtin_amdgcn_global_load_lds(
                (const __attribute__((address_space(1))) void*)g,
                (__attribute__((address_space(3))) void*)&tile[blk << 8],
                16, 0, 0);
        }
        asm volatile("s_waitcnt vmcnt(0)" ::: "memory");
    } else {
        // edge chunk (cv == NVCH-1): scalar bounds-checked path, same layout
        int trow = tid >> 4;
        int m    = tid & 15;
        #pragma unroll
        for (int p = 0; p < 4; ++p) {
            int d = trow + (p << 4);
            const float* rowp = weight + (size_t)(d0 + d) * VOCAB;
            int o = (d << 6) + (((m + (d >> 2)) & 15) << 2);
            #pragma unroll
            for (int k = 0; k < 4; ++k) {
                int v = v0 + (m << 2) + k;
                tile[o + k] = (v < VOCAB) ? rowp[v] : 0.f;
            }
        }
    }
    __syncthreads();

    // write phase: 16 lanes x 4 dims per token; 4 b32 tile reads + one NT
    // dwordx4 store per token-slice; 16 tokens in parallel.
    int tl = tid >> 4;                     // token slot group 0..15
    int g  = tid & 15;                     // d-group 0..15 (d = 4g+k, d>>2 = g)
    int g4 = g << 2;
    float4 b4 = *reinterpret_cast<const float4*>(bias + d0 + g4);
    int n = snn;
    for (int i = tl; i < n; i += 16) {
        unsigned e = slist[i];
        int vl = (int)(e & 63);
        size_t t = e >> 6;
        int base = (g4 << 6) + ((((vl >> 2) + g) & 15) << 2) + (vl & 3);
        f32x4 o;
        o.x = tile[base      ] + b4.x;     // d = 4g+0
        o.y = tile[base +  64] + b4.y;     // d = 4g+1
        o.z = tile[base + 128] + b4.z;     // d = 4g+2
        o.w = tile[base + 192] + b4.w;     // d = 4g+3
        // non-temporal: out is write-once -> don't evict weight from L3
        __builtin_nontemporal_store(o, reinterpret_cast<f32x4*>(out + t * NUM_DIM + d0 + g4));
    }

    // cold overflow path (n_ov == 0 for random tokens): cv==0 blocks cover it
    if (cv == 0) {
        int nov = *n_ov;
        if (nov > 0) {
            int d = tid & 63;
            float b = bias[d0 + d];
            for (int i = tid >> 6; i < nov; i += 4) {
                int t = ov_list[i];
                int v = tokens[t];
                out[(size_t)t * NUM_DIM + d0 + d] = weight[(size_t)(d0 + d) * VOCAB + v] + b;
            }
        }
    }
}

// ---------------- naive fallback if ws too small ----------------

__global__ void __launch_bounds__(256) token_embed_naive(
    const int* __restrict__ tokens, const float* __restrict__ weight,
    const float* __restrict__ bias, float* __restrict__ out, int n_tok)
{
    int t = blockIdx.x;
    if (t >= n_tok) return;
    int tok = tokens[t];
    int dd = threadIdx.x * 4;
    const float* wcol = weight + tok;
    float4 b4 = *reinterpret_cast<const float4*>(bias + dd);
    float4 o;
    o.x = wcol[(size_t)(dd + 0) * VOCAB] + b4.x;
    o.y = wcol[(size_t)(dd + 1) * VOCAB] + b4.y;
    o.z = wcol[(size_t)(dd + 2) * VOCAB] + b4.z;
    o.w = wcol[(size_t)(dd + 3) * VOCAB] + b4.w;
    *reinterpret_cast<float4*>(out + (size_t)t * NUM_DIM + dd) = o;
}

extern "C" void kernel_launch(void* const* d_in, const int* in_sizes, int n_in,
                              void* d_out, int out_size, void* d_ws, size_t ws_size,
                              hipStream_t stream)
{
    const int*   tokens = (const int*)d_in[0];
    const float* weight = (const float*)d_in[1];
    const float* bias   = (const float*)d_in[2];
    float*       out    = (float*)d_out;
    int n_tok = in_sizes[0];               // 16384

    // ws layout (ints): ccount[NVCH] | n_ov[64] | ov_list[n_tok] | clist[NVCH*CLCAP]
    size_t need_ints = (size_t)NVCH + 64 + (size_t)n_tok + (size_t)NVCH * CLCAP;
    if (ws_size < need_ints * sizeof(int)) {
        token_embed_naive<<<n_tok, 256, 0, stream>>>(tokens, weight, bias, out, n_tok);
        return;
    }

    int*      ccount  = (int*)d_ws;
    int*      n_ov    = ccount + NVCH;
    int*      ov_list = n_ov + 64;
    unsigned* clist   = (unsigned*)(ov_list + n_tok);

    // zero ccount + n_ov in one capturable memset (they are adjacent)
    (void)hipMemsetAsync(ccount, 0, (size_t)(NVCH + 64) * sizeof(int), stream);

    scatter_kernel<<<(n_tok + 255) / 256, 256, 0, stream>>>(
        tokens, n_tok, ccount, clist, n_ov, ov_list);

    dim3 grid(NDCH, NVCH);                 // (16, 786): d-chunk fast axis
    embed_main<<<grid, 256, 0, stream>>>(weight, bias, ccount, clist, out,
                                         tokens, n_ov, ov_list);
}

// Round 12
// 60.714 us; speedup vs baseline: 1.0092x; 1.0092x over previous
//
#include <hip/hip_runtime.h>
#include <hip/hip_bf16.h>

#define VOCAB   50257
#define NUM_DIM 1024
#define VB 64                              // vocab entries per tile
#define DB 64                              // dims per tile
#define NVCH ((VOCAB + VB - 1) / VB)       // 786 vocab chunks
#define CLCAP 96                           // list capacity per chunk (mean ~21)
#define NDCH (NUM_DIM / DB)                // 16 dim chunks

typedef float f32x4 __attribute__((ext_vector_type(4)));  // NT-store-compatible

// Round-9 configuration (best verified: 60.4us). Rounds 7/11 proved that
// removing the memset->scatter->main dispatch chain via cooperative launch
// (+400us) or device-scope spin barriers (queue hang) is NOT viable on
// MI355X; the ~5-7us chain cost is structural.
// Swizzled flat tile, 16KB: offset(v,d) = v*64 + (((d>>2)+(v>>2))&15)*4 + (d&3)
//  - load phase scalar stores: 2 lanes/bank (free)
//  - write phase b128 reads: uniform banks (free), 16B-aligned

// ---------------- scatter: bucket tokens by vocab chunk ----------------

__global__ void __launch_bounds__(256) scatter_kernel(
    const int* __restrict__ tokens, int n_tok,
    int* ccount, unsigned* clist, int* n_ov, int* ov_list)
{
    int i = blockIdx.x * 256 + threadIdx.x;
    if (i >= n_tok) return;
    int v = tokens[i];
    int ch = v >> 6;                                   // vocab chunk (VB=64)
    int slot = atomicAdd(&ccount[ch], 1);
    if (slot < CLCAP) clist[ch * CLCAP + slot] = ((unsigned)i << 6) | (unsigned)(v & 63);
    else { int p = atomicAdd(n_ov, 1); ov_list[p] = i; }
}

// ---------------- main: stream weight once, scatter to output rows ----------------

__global__ void __launch_bounds__(256, 8) embed_main(
    const float* __restrict__ weight, const float* __restrict__ bias,
    const int* __restrict__ ccount, const unsigned* __restrict__ clist,
    float* __restrict__ out,
    const int* __restrict__ tokens, const int* __restrict__ n_ov,
    const int* __restrict__ ov_list)
{
    __shared__ __align__(16) float tile[VB * DB];   // swizzled, 16 KB
    __shared__ unsigned slist[CLCAP];
    __shared__ int snn;

    int tid = threadIdx.x;
    int cv = blockIdx.y;
    int v0 = cv * VB;
    int d0 = blockIdx.x * DB;

    if (tid == 0) { int c = ccount[cv]; snn = c < CLCAP ? c : CLCAP; }
    if (tid < CLCAP) slist[tid] = clist[cv * CLCAP + tid];

    // tile load: coalesced float4 along vocab, swizzled scatter into LDS
    int trow = tid >> 4;                   // d-offset base 0..15
    int m    = tid & 15;                   // v-group index (v>>2 for this thread)
    int tcol = m << 2;                     // v-offset 0..60
    const float* gp = weight + (size_t)(d0 + trow) * VOCAB + v0 + tcol;
    if (v0 + VB <= VOCAB) {                // block-uniform fast path (all but cv=785)
        #pragma unroll
        for (int p = 0; p < 4; ++p) {
            float4 w = *reinterpret_cast<const float4*>(gp);
            gp += (size_t)16 * VOCAB;
            int d = trow + (p << 4);
            int o = tcol * 64 + ((((d >> 2) + m) & 15) << 2) + (d & 3);
            tile[o + 0 * 64] = w.x;        // v = 4m+0..3: 2 lanes/bank (free)
            tile[o + 1 * 64] = w.y;
            tile[o + 2 * 64] = w.z;
            tile[o + 3 * 64] = w.w;
        }
    } else {
        #pragma unroll
        for (int p = 0; p < 4; ++p) {
            int d = trow + (p << 4);
            const float* rowp = weight + (size_t)(d0 + d) * VOCAB;
            int o = tcol * 64 + ((((d >> 2) + m) & 15) << 2) + (d & 3);
            #pragma unroll
            for (int k = 0; k < 4; ++k) {
                int v = v0 + tcol + k;
                tile[o + k * 64] = (v < VOCAB) ? rowp[v] : 0.f;
            }
        }
    }
    __syncthreads();

    // write phase: 16 lanes x 4 dims per token; one b128 read + one NT dwordx4
    int tl = tid >> 4;                     // token slot group 0..15
    int g  = tid & 15;                     // d-group 0..15
    float4 b4 = *reinterpret_cast<const float4*>(bias + d0 + (g << 2));
    int n = snn;
    for (int i = tl; i < n; i += 16) {
        unsigned e = slist[i];
        int vl = e & 63;
        size_t t = e >> 6;
        int s = ((g + (vl >> 2)) & 15) << 2;
        float4 w4 = *reinterpret_cast<const float4*>(&tile[vl * 64 + s]);
        f32x4 o;
        o.x = w4.x + b4.x;
        o.y = w4.y + b4.y;
        o.z = w4.z + b4.z;
        o.w = w4.w + b4.w;
        // non-temporal: out is write-once -> don't evict weight from L3
        __builtin_nontemporal_store(o, reinterpret_cast<f32x4*>(out + t * NUM_DIM + d0 + (g << 2)));
    }

    // cold overflow path (n_ov == 0 for random tokens): cv==0 blocks cover it
    if (cv == 0) {
        int nov = *n_ov;
        if (nov > 0) {
            int d = tid & 63;
            float b = bias[d0 + d];
            for (int i = tid >> 6; i < nov; i += 4) {
                int t = ov_list[i];
                int v = tokens[t];
                out[(size_t)t * NUM_DIM + d0 + d] = weight[(size_t)(d0 + d) * VOCAB + v] + b;
            }
        }
    }
}

// ---------------- naive fallback if ws too small ----------------

__global__ void __launch_bounds__(256) token_embed_naive(
    const int* __restrict__ tokens, const float* __restrict__ weight,
    const float* __restrict__ bias, float* __restrict__ out, int n_tok)
{
    int t = blockIdx.x;
    if (t >= n_tok) return;
    int tok = tokens[t];
    int dd = threadIdx.x * 4;
    const float* wcol = weight + tok;
    float4 b4 = *reinterpret_cast<const float4*>(bias + dd);
    float4 o;
    o.x = wcol[(size_t)(dd + 0) * VOCAB] + b4.x;
    o.y = wcol[(size_t)(dd + 1) * VOCAB] + b4.y;
    o.z = wcol[(size_t)(dd + 2) * VOCAB] + b4.z;
    o.w = wcol[(size_t)(dd + 3) * VOCAB] + b4.w;
    *reinterpret_cast<float4*>(out + (size_t)t * NUM_DIM + dd) = o;
}

extern "C" void kernel_launch(void* const* d_in, const int* in_sizes, int n_in,
                              void* d_out, int out_size, void* d_ws, size_t ws_size,
                              hipStream_t stream)
{
    const int*   tokens = (const int*)d_in[0];
    const float* weight = (const float*)d_in[1];
    const float* bias   = (const float*)d_in[2];
    float*       out    = (float*)d_out;
    int n_tok = in_sizes[0];               // 16384

    // ws layout (ints): ccount[NVCH] | n_ov[64] | ov_list[n_tok] | clist[NVCH*CLCAP]
    size_t need_ints = (size_t)NVCH + 64 + (size_t)n_tok + (size_t)NVCH * CLCAP;
    if (ws_size < need_ints * sizeof(int)) {
        token_embed_naive<<<n_tok, 256, 0, stream>>>(tokens, weight, bias, out, n_tok);
        return;
    }

    int*      ccount  = (int*)d_ws;
    int*      n_ov    = ccount + NVCH;
    int*      ov_list = n_ov + 64;
    unsigned* clist   = (unsigned*)(ov_list + n_tok);

    // zero ccount + n_ov in one capturable memset (they are adjacent)
    (void)hipMemsetAsync(ccount, 0, (size_t)(NVCH + 64) * sizeof(int), stream);

    scatter_kernel<<<(n_tok + 255) / 256, 256, 0, stream>>>(
        tokens, n_tok, ccount, clist, n_ov, ov_list);

    dim3 grid(NDCH, NVCH);                 // (16, 786): d-chunk fast axis
    embed_main<<<grid, 256, 0, stream>>>(weight, bias, ccount, clist, out,
                                         tokens, n_ov, ov_list);
}